// Round 1
// baseline (1588.054 us; speedup 1.0000x reference)
//
#include <hip/hip_runtime.h>
#include <hip/hip_bf16.h>
#include <stdint.h>

#define NTOK 131072
#define NEXP 8

typedef unsigned short ushortT;
typedef __attribute__((ext_vector_type(4))) float f32x4;
typedef __attribute__((ext_vector_type(8))) short s16x8;
typedef __attribute__((ext_vector_type(8))) __bf16 bf16x8;

__device__ __forceinline__ float bfu2f(unsigned short u){
  union { float f; uint32_t i; } c; c.i = ((uint32_t)u) << 16; return c.f;
}
__device__ __forceinline__ unsigned short f2bfu(float f){
  union { float f; uint32_t i; } c; c.f = f;
  uint32_t x = c.i;
  uint32_t r = (x + 0x7fffu + ((x >> 16) & 1u)) >> 16;  // RNE
  return (unsigned short)r;
}
// tanh-approx GELU (max abs err ~1e-3, well under 7e-2 threshold; exact erff is ~3x slower)
__device__ __forceinline__ float gelu_f(float x){
  float u = 0.7978845608028654f * (x + 0.044715f * x * x * x);
  float e = __expf(2.0f * u);
  float t = 1.0f - 2.0f / (e + 1.0f);
  return 0.5f * x * (1.0f + t);
}
__device__ __forceinline__ bf16x8 ldfrag(const void* p){
  s16x8 v = *(const s16x8*)p;
  return __builtin_bit_cast(bf16x8, v);
}

// ---- convert W1 [E][D][H] / W2 [E][H][O] fp32 -> bf16, transposed to [E][n][k] ----
__global__ __launch_bounds__(256) void prep_w_kernel(const float* __restrict__ W1,
                                                     const float* __restrict__ W2,
                                                     ushortT* __restrict__ W1bf,
                                                     ushortT* __restrict__ W2bf){
  int bid = blockIdx.x;
  const float* src; ushortT* dst;
  if (bid < 512){ src = W1; dst = W1bf; } else { src = W2; dst = W2bf; bid -= 512; }
  int e = bid >> 6; int t = bid & 63;
  int r0 = (t >> 3) * 64;   // k block
  int c0 = (t & 7) * 64;    // n block
  __shared__ ushortT tileT[64][72];
  for (int i = threadIdx.x; i < 4096; i += 256){
    int r = i >> 6, c = i & 63;
    float v = src[((size_t)(e*512 + r0 + r))*512 + c0 + c];
    tileT[c][r] = f2bfu(v);
  }
  __syncthreads();
  for (int i = threadIdx.x; i < 4096; i += 256){
    int r = i >> 6, c = i & 63;
    dst[((size_t)(e*512 + c0 + r))*512 + r0 + c] = tileT[r][c];
  }
}

// ---- gating: logits(fp32) -> top2 -> weights; also emit x as bf16 ----
__global__ __launch_bounds__(256) void gating_kernel(const float* __restrict__ x,
                                                     const float* __restrict__ Wg,
                                                     ushortT* __restrict__ xbf,
                                                     int* __restrict__ epair,
                                                     float* __restrict__ wt){
  int l = threadIdx.x & 63;
  int wv = threadIdx.x >> 6;
  f32x4 wgv[16];                       // Wg rows l*8..l*8+7 (8 experts each) in regs
  #pragma unroll
  for (int i = 0; i < 8; i++){
    const f32x4* p = (const f32x4*)(Wg + (size_t)(l*8 + i)*8);
    wgv[2*i] = p[0]; wgv[2*i+1] = p[1];
  }
  int tbase = (blockIdx.x * 4 + wv) * 16;
  for (int tt = 0; tt < 16; tt++){
    int t = tbase + tt;
    const f32x4* xr = (const f32x4*)(x + (size_t)t*512 + l*8);
    f32x4 xa = xr[0], xb = xr[1];
    float acc[8];
    #pragma unroll
    for (int e2 = 0; e2 < 8; e2++) acc[e2] = 0.f;
    #pragma unroll
    for (int i = 0; i < 4; i++){
      float xi = xa[i], xj = xb[i];
      #pragma unroll
      for (int e2 = 0; e2 < 4; e2++){
        acc[e2]   += xi * wgv[2*i][e2];
        acc[4+e2] += xi * wgv[2*i+1][e2];
        acc[e2]   += xj * wgv[2*(i+4)][e2];
        acc[4+e2] += xj * wgv[2*(i+4)+1][e2];
      }
    }
    #pragma unroll
    for (int off = 1; off < 64; off <<= 1){
      #pragma unroll
      for (int e2 = 0; e2 < 8; e2++) acc[e2] += __shfl_xor(acc[e2], off);
    }
    // top2, ties -> lower index (matches lax.top_k)
    int e0 = 0; float v0 = acc[0];
    #pragma unroll
    for (int e2 = 1; e2 < 8; e2++) if (acc[e2] > v0){ v0 = acc[e2]; e0 = e2; }
    int e1 = -1; float v1 = -3.4e38f;
    #pragma unroll
    for (int e2 = 0; e2 < 8; e2++){ if (e2 != e0 && acc[e2] > v1){ v1 = acc[e2]; e1 = e2; } }
    float w0 = 1.f / (1.f + __expf(v1 - v0));   // == p0/(p0+p1) after softmax
    if (l == 0){
      epair[t] = e0 | (e1 << 4);
      wt[t] = w0;
      wt[NTOK + t] = 1.f - w0;
    }
    s16x8 o;
    #pragma unroll
    for (int j = 0; j < 4; j++){ o[j] = (short)f2bfu(xa[j]); o[4+j] = (short)f2bfu(xb[j]); }
    *(s16x8*)(xbf + (size_t)t*512 + l*8) = o;
  }
}

// ---- routing scatter: per-(slot,expert) token lists ----
__global__ __launch_bounds__(256) void scatter_kernel(const int* __restrict__ epair,
                                                      int* __restrict__ cursors,
                                                      int* __restrict__ lists){
  __shared__ int cntL[16]; __shared__ int baseL[16];
  int tid = threadIdx.x;
  if (tid < 16) cntL[tid] = 0;
  __syncthreads();
  int t = blockIdx.x * 256 + tid;
  int p = epair[t];
  int e0 = p & 15, e1 = (p >> 4) & 15;
  int lp0 = atomicAdd(&cntL[e0], 1);
  int lp1 = atomicAdd(&cntL[8 + e1], 1);
  __syncthreads();
  if (tid < 16) baseL[tid] = atomicAdd(&cursors[tid], cntL[tid]);
  __syncthreads();
  lists[(size_t)e0 * NTOK + baseL[e0] + lp0] = t;
  lists[(size_t)(8 + e1) * NTOK + baseL[8 + e1] + lp1] = t;
}

// ---- fused expert MLP: 64-token tile, GEMM1 -> LN -> gelu -> GEMM2 -> weighted out ----
template<int SLOT>
__global__ __launch_bounds__(512, 2) void expert_kernel(
    const ushortT* __restrict__ xbf, const ushortT* __restrict__ W1bf,
    const ushortT* __restrict__ W2bf, const float* __restrict__ gamma,
    const float* __restrict__ beta, const float* __restrict__ wt,
    const int* __restrict__ cursors, const int* __restrict__ lists,
    float* __restrict__ out)
{
  __shared__ int4 XsB[2][512];       // 16 KB  X tile [64][64] bf16, swizzled
  __shared__ int4 WsB[2][1024];      // 32 KB  W tile [128][64] bf16, swizzled
  __shared__ ushortT hB[64 * 512];   // 64 KB  h, rows 1024B, swizzled (row&7)<<4
  __shared__ int   toksL[64];
  __shared__ float wrowL[64];
  __shared__ float wsumL[512];
  __shared__ float wsqL[512];
  __shared__ float muL[64];
  __shared__ float rsL[64];

  int tid = threadIdx.x;
  int w = tid >> 6;
  int l = tid & 63;

  // block -> (expert, tile)
  int e = -1, tile = 0, bacc = 0, cn = 0;
  #pragma unroll
  for (int i = 0; i < 8; i++){
    int c = cursors[SLOT*8 + i];
    int nt = (c + 63) >> 6;
    if (e < 0 && (int)blockIdx.x < bacc + nt){ e = i; tile = (int)blockIdx.x - bacc; cn = c; }
    bacc += nt;
  }
  if (e < 0) return;
  int tb = tile * 64;

  if (tid < 64){
    int idx = tb + tid;
    int tok = (idx < cn) ? lists[(size_t)(SLOT*8 + e) * NTOK + idx] : -1;
    toksL[tid] = tok;
    wrowL[tid] = (tok >= 0) ? wt[(size_t)SLOT*NTOK + tok] : 0.f;
  }
  wsumL[tid] = 0.f; wsqL[tid] = 0.f;
  __syncthreads();

  int srow = tid >> 3;            // staging row 0..63 (row+64 shares kb since 64%8==0)
  int cs   = tid & 7;             // swizzled 16B chunk in 128B row
  int kb   = cs ^ (srow & 7);     // true chunk index
  int tokS = toksL[srow]; if (tokS < 0) tokS = toksL[0];
  const int4* xrow = (const int4*)(xbf + (size_t)tokS * 512);
  const ushortT* w1base = W1bf + (size_t)e * 512 * 512;
  const ushortT* w2base = W2bf + (size_t)e * 512 * 512;
  int swz = (l & 7) << 4;

  // ================= GEMM1: h = x @ W1 (4 chunks of 128 cols) =================
  for (int c = 0; c < 4; c++){
    f32x4 acc[4];
    #pragma unroll
    for (int m = 0; m < 4; m++) acc[m] = (f32x4){0.f,0.f,0.f,0.f};
    const int4* wr1 = (const int4*)(w1base + (size_t)(c*128 + srow) * 512);
    const int4* wr2 = (const int4*)(w1base + (size_t)(c*128 + 64 + srow) * 512);
    // prologue: stage kt=0 -> buf0
    XsB[0][tid] = xrow[kb];
    WsB[0][tid] = wr1[kb];
    WsB[0][tid + 512] = wr2[kb];
    for (int kt = 0; kt < 8; kt++){
      int b = kt & 1;
      __syncthreads();
      int4 vx = {0,0,0,0}, vw1 = {0,0,0,0}, vw2 = {0,0,0,0};
      if (kt < 7){                               // issue next-tile loads before MFMAs
        vx  = xrow[(kt+1)*8 + kb];
        vw1 = wr1[(kt+1)*8 + kb];
        vw2 = wr2[(kt+1)*8 + kb];
      }
      const char* Xp = (const char*)&XsB[b][0];
      const char* Wp = (const char*)&WsB[b][0];
      #pragma unroll
      for (int ks = 0; ks < 2; ks++){
        int koff = (ks*64 + ((l >> 4)*16)) ^ swz;
        bf16x8 B = ldfrag(Wp + (w*16 + (l&15))*128 + koff);
        #pragma unroll
        for (int m = 0; m < 4; m++){
          bf16x8 A = ldfrag(Xp + (m*16 + (l&15))*128 + koff);
          acc[m] = __builtin_amdgcn_mfma_f32_16x16x32_bf16(A, B, acc[m], 0, 0, 0);
        }
      }
      if (kt < 7){ int bn = b ^ 1; XsB[bn][tid] = vx; WsB[bn][tid] = vw1; WsB[bn][tid+512] = vw2; }
    }
    // chunk epilogue: raw h -> LDS (bf16, swizzled) + LN partials
    int colbase = c*128 + w*16 + (l & 15);
    #pragma unroll
    for (int m = 0; m < 4; m++){
      #pragma unroll
      for (int j = 0; j < 4; j++){
        float v = acc[m][j];
        int row = m*16 + ((l >> 4) << 2) + j;
        int byt = row*1024 + ((colbase*2) ^ ((row & 7) << 4));
        *(ushortT*)((char*)hB + byt) = f2bfu(v);
        float s = v, q = v*v;
        s += __shfl_xor(s, 1); q += __shfl_xor(q, 1);
        s += __shfl_xor(s, 2); q += __shfl_xor(q, 2);
        s += __shfl_xor(s, 4); q += __shfl_xor(q, 4);
        s += __shfl_xor(s, 8); q += __shfl_xor(q, 8);
        if ((l & 15) == 0){
          wsumL[w*64 + row] += s;
          wsqL [w*64 + row] += q;
        }
      }
    }
  }
  __syncthreads();

  // ================= LayerNorm stats + normalize + gelu sweep =================
  if (tid < 64){
    float s = 0.f, q = 0.f;
    #pragma unroll
    for (int i = 0; i < 8; i++){ s += wsumL[i*64 + tid]; q += wsqL[i*64 + tid]; }
    float mu = s * (1.f/512.f);
    float var = q * (1.f/512.f) - mu*mu;   // biased, as torch LayerNorm
    muL[tid] = mu;
    rsL[tid] = rsqrtf(var + 1e-5f);
  }
  __syncthreads();
  {
    const float* ga = gamma + (size_t)e*512;
    const float* be = beta  + (size_t)e*512;
    #pragma unroll
    for (int i = 0; i < 8; i++){
      int idx = tid + i*512;
      int row = idx >> 6;
      int kbyte = ((idx & 63) * 16) ^ ((row & 7) << 4);
      int k0 = kbyte >> 1;
      s16x8 u = *(s16x8*)((char*)hB + idx*16);
      float mu = muL[row], rs = rsL[row];
      f32x4 g0 = *(const f32x4*)(ga + k0);
      f32x4 g1 = *(const f32x4*)(ga + k0 + 4);
      f32x4 b0 = *(const f32x4*)(be + k0);
      f32x4 b1 = *(const f32x4*)(be + k0 + 4);
      s16x8 o;
      #pragma unroll
      for (int j = 0; j < 8; j++){
        float v = bfu2f((unsigned short)u[j]);
        float gg = (j < 4) ? g0[j] : g1[j-4];
        float bb = (j < 4) ? b0[j] : b1[j-4];
        v = (v - mu)*rs*gg + bb;
        o[j] = (short)f2bfu(gelu_f(v));
      }
      *(s16x8*)((char*)hB + idx*16) = o;
    }
  }
  __syncthreads();

  // ================= GEMM2: y = h @ W2, weighted store =================
  for (int oc = 0; oc < 4; oc++){
    f32x4 acc[4];
    #pragma unroll
    for (int m = 0; m < 4; m++) acc[m] = (f32x4){0.f,0.f,0.f,0.f};
    const int4* wr1 = (const int4*)(w2base + (size_t)(oc*128 + srow) * 512);
    const int4* wr2 = (const int4*)(w2base + (size_t)(oc*128 + 64 + srow) * 512);
    WsB[0][tid] = wr1[kb];
    WsB[0][tid + 512] = wr2[kb];
    for (int kt = 0; kt < 8; kt++){
      int b = kt & 1;
      __syncthreads();
      int4 vw1 = {0,0,0,0}, vw2 = {0,0,0,0};
      if (kt < 7){ vw1 = wr1[(kt+1)*8 + kb]; vw2 = wr2[(kt+1)*8 + kb]; }
      const char* Wp = (const char*)&WsB[b][0];
      #pragma unroll
      for (int ks = 0; ks < 2; ks++){
        int koff = (ks*64 + ((l >> 4)*16)) ^ swz;
        bf16x8 B = ldfrag(Wp + (w*16 + (l&15))*128 + koff);
        #pragma unroll
        for (int m = 0; m < 4; m++){
          int hbyte = (m*16 + (l&15))*1024 + ((kt*128 + ks*64 + ((l >> 4)*16)) ^ swz);
          bf16x8 A = ldfrag((const char*)hB + hbyte);
          acc[m] = __builtin_amdgcn_mfma_f32_16x16x32_bf16(A, B, acc[m], 0, 0, 0);
        }
      }
      if (kt < 7){ int bn = b ^ 1; WsB[bn][tid] = vw1; WsB[bn][tid+512] = vw2; }
    }
    int colb = oc*128 + w*16 + (l & 15);
    #pragma unroll
    for (int m = 0; m < 4; m++){
      #pragma unroll
      for (int j = 0; j < 4; j++){
        int row = m*16 + ((l >> 4) << 2) + j;
        int tok = toksL[row];
        if (tok >= 0){
          float val = acc[m][j] * wrowL[row];
          float* p = out + (size_t)tok*512 + colb;
          if (SLOT == 0) *p = val; else *p += val;
        }
      }
    }
  }
}

extern "C" void kernel_launch(void* const* d_in, const int* in_sizes, int n_in,
                              void* d_out, int out_size, void* d_ws, size_t ws_size,
                              hipStream_t stream){
  const float* x     = (const float*)d_in[0];
  const float* Wg    = (const float*)d_in[1];
  const float* W1    = (const float*)d_in[2];
  const float* gamma = (const float*)d_in[3];
  const float* beta  = (const float*)d_in[4];
  const float* W2    = (const float*)d_in[5];
  float* out = (float*)d_out;

  char* ws = (char*)d_ws;
  size_t off = 0;
  ushortT* xbf   = (ushortT*)(ws + off); off += (size_t)NTOK*512*2;      // 128 MB
  ushortT* W1bf  = (ushortT*)(ws + off); off += (size_t)8*512*512*2;     // 4 MB
  ushortT* W2bf  = (ushortT*)(ws + off); off += (size_t)8*512*512*2;     // 4 MB
  int*     lists = (int*)(ws + off);     off += (size_t)16*NTOK*4;       // 8 MB
  float*   wtp   = (float*)(ws + off);   off += (size_t)2*NTOK*4;        // 1 MB
  int*     epair = (int*)(ws + off);     off += (size_t)NTOK*4;          // 0.5 MB
  int*     cursors = (int*)(ws + off);   off += 256;

  hipMemsetAsync(cursors, 0, 64, stream);
  prep_w_kernel<<<1024, 256, 0, stream>>>(W1, W2, W1bf, W2bf);
  gating_kernel<<<NTOK/64, 256, 0, stream>>>(x, Wg, xbf, epair, wtp);
  scatter_kernel<<<NTOK/256, 256, 0, stream>>>(epair, cursors, lists);
  expert_kernel<0><<<2056, 512, 0, stream>>>(xbf, W1bf, W2bf, gamma, beta, wtp, cursors, lists, out);
  expert_kernel<1><<<2056, 512, 0, stream>>>(xbf, W1bf, W2bf, gamma, beta, wtp, cursors, lists, out);
}

// Round 4
// 639.821 us; speedup vs baseline: 2.4820x; 2.4820x over previous
//
#include <hip/hip_runtime.h>
#include <hip/hip_bf16.h>
#include <stdint.h>

#define NTOK 131072
#define NEXP 8

typedef unsigned short ushortT;
typedef __attribute__((ext_vector_type(4))) float f32x4;
typedef __attribute__((ext_vector_type(8))) short s16x8;
typedef __attribute__((ext_vector_type(8))) __bf16 bf16x8;

__device__ __forceinline__ float bfu2f(unsigned short u){
  union { float f; uint32_t i; } c; c.i = ((uint32_t)u) << 16; return c.f;
}
__device__ __forceinline__ unsigned short f2bfu(float f){
  union { float f; uint32_t i; } c; c.f = f;
  uint32_t x = c.i;
  uint32_t r = (x + 0x7fffu + ((x >> 16) & 1u)) >> 16;  // RNE
  return (unsigned short)r;
}
// tanh-approx GELU (max abs err ~1e-3 vs erf form; threshold is 7e-2)
__device__ __forceinline__ float gelu_f(float x){
  float u = 0.7978845608028654f * (x + 0.044715f * x * x * x);
  float e = __expf(2.0f * u);
  float t = 1.0f - 2.0f / (e + 1.0f);
  return 0.5f * x * (1.0f + t);
}
__device__ __forceinline__ bf16x8 ldfrag(const void* p){
  s16x8 v = *(const s16x8*)p;
  return __builtin_bit_cast(bf16x8, v);
}

// ---- zero the routing cursors (kernel node instead of memset node) ----
__global__ __launch_bounds__(64) void zero_cursors_kernel(int* __restrict__ cursors){
  if (threadIdx.x < 16) cursors[threadIdx.x] = 0;
}

// ---- pack W1 [E][D][H] / W2 [E][H][O] fp32 -> bf16 MFMA B-fragment order ----
// frag id fi = (e*32 + nb)*16 + kt*2 + ks   (nb = n/16, kt = k/64, ks = (k/32)&1)
// frag layout: lane l, elem j (8 per lane, 16B) = W[k0 + (l>>4)*8 + j][nb*16 + (l&15)]
__global__ __launch_bounds__(256) void prep_w_kernel(const float* __restrict__ W1,
                                                     const float* __restrict__ W2,
                                                     ushortT* __restrict__ W1f,
                                                     ushortT* __restrict__ W2f){
  int bid = blockIdx.x;   // 1024 = 2 mats * 8 e * 8 ktile * 8 ntile
  const float* src; ushortT* dst;
  if (bid < 512){ src = W1; dst = W1f; } else { src = W2; dst = W2f; bid -= 512; }
  int e  = bid >> 6;
  int kt = (bid >> 3) & 7;
  int nt = bid & 7;
  __shared__ ushortT tileT[64][68];   // [n_local][k_local]
  int t = threadIdx.x;
  #pragma unroll
  for (int i = 0; i < 16; i++){
    int idx = t + i*256;
    int r = idx >> 6, c = idx & 63;   // r = k_local, c = n_local
    float v = src[((size_t)(e*512 + kt*64 + r))*512 + nt*64 + c];
    tileT[c][r] = f2bfu(v);
  }
  __syncthreads();
  int sub = t >> 6, l = t & 63;
  #pragma unroll
  for (int fo = 0; fo < 2; fo++){
    int fr  = sub + fo*4;             // local frag 0..7
    int nbl = fr >> 1;                // 0..3
    int ks  = fr & 1;
    int nb  = nt*4 + nbl;
    size_t fi = ((size_t)(e*32 + nb))*16 + kt*2 + ks;
    ushortT tmp[8];
    #pragma unroll
    for (int j = 0; j < 8; j++)
      tmp[j] = tileT[nbl*16 + (l & 15)][ks*32 + (l >> 4)*8 + j];
    *(s16x8*)(dst + fi*512 + l*8) = *(s16x8*)tmp;
  }
}

// ---- gating: logits(fp32) -> top2 -> weights; also emit x as bf16 ----
__global__ __launch_bounds__(256) void gating_kernel(const float* __restrict__ x,
                                                     const float* __restrict__ Wg,
                                                     ushortT* __restrict__ xbf,
                                                     int* __restrict__ epair,
                                                     float* __restrict__ wt){
  int l = threadIdx.x & 63;
  int wv = threadIdx.x >> 6;
  f32x4 wgv[16];
  #pragma unroll
  for (int i = 0; i < 8; i++){
    const f32x4* p = (const f32x4*)(Wg + (size_t)(l*8 + i)*8);
    wgv[2*i] = p[0]; wgv[2*i+1] = p[1];
  }
  int tbase = (blockIdx.x * 4 + wv) * 16;
  for (int tt = 0; tt < 16; tt++){
    int t = tbase + tt;
    const f32x4* xr = (const f32x4*)(x + (size_t)t*512 + l*8);
    f32x4 xa = xr[0], xb = xr[1];
    float acc[8];
    #pragma unroll
    for (int e2 = 0; e2 < 8; e2++) acc[e2] = 0.f;
    #pragma unroll
    for (int i = 0; i < 4; i++){
      float xi = xa[i], xj = xb[i];
      #pragma unroll
      for (int e2 = 0; e2 < 4; e2++){
        acc[e2]   += xi * wgv[2*i][e2];
        acc[4+e2] += xi * wgv[2*i+1][e2];
        acc[e2]   += xj * wgv[2*(i+4)][e2];
        acc[4+e2] += xj * wgv[2*(i+4)+1][e2];
      }
    }
    #pragma unroll
    for (int off = 1; off < 64; off <<= 1){
      #pragma unroll
      for (int e2 = 0; e2 < 8; e2++) acc[e2] += __shfl_xor(acc[e2], off);
    }
    int e0 = 0; float v0 = acc[0];
    #pragma unroll
    for (int e2 = 1; e2 < 8; e2++) if (acc[e2] > v0){ v0 = acc[e2]; e0 = e2; }
    int e1 = -1; float v1 = -3.4e38f;
    #pragma unroll
    for (int e2 = 0; e2 < 8; e2++){ if (e2 != e0 && acc[e2] > v1){ v1 = acc[e2]; e1 = e2; } }
    float w0 = 1.f / (1.f + __expf(v1 - v0));
    if (l == 0){
      epair[t] = e0 | (e1 << 4);
      wt[t] = w0;
      wt[NTOK + t] = 1.f - w0;
    }
    s16x8 o;
    #pragma unroll
    for (int j = 0; j < 4; j++){ o[j] = (short)f2bfu(xa[j]); o[4+j] = (short)f2bfu(xb[j]); }
    *(s16x8*)(xbf + (size_t)t*512 + l*8) = o;
  }
}

// ---- routing scatter ----
__global__ __launch_bounds__(256) void scatter_kernel(const int* __restrict__ epair,
                                                      int* __restrict__ cursors,
                                                      int* __restrict__ lists){
  __shared__ int cntL[16]; __shared__ int baseL[16];
  int tid = threadIdx.x;
  if (tid < 16) cntL[tid] = 0;
  __syncthreads();
  int t = blockIdx.x * 256 + tid;
  int p = epair[t];
  int e0 = p & 15, e1 = (p >> 4) & 15;
  int lp0 = atomicAdd(&cntL[e0], 1);
  int lp1 = atomicAdd(&cntL[8 + e1], 1);
  __syncthreads();
  if (tid < 16) baseL[tid] = atomicAdd(&cursors[tid], cntL[tid]);
  __syncthreads();
  lists[(size_t)e0 * NTOK + baseL[e0] + lp0] = t;
  lists[(size_t)(8 + e1) * NTOK + baseL[8 + e1] + lp1] = t;
}

// ---- fused expert MLP: 64-token tile, barrier-free GEMM K-loops ----
// LDS: one 64KB buffer holds X during GEMM1, then h during GEMM2.
// W1/W2 come fragment-packed from global (L2-resident), never staged.
// __launch_bounds__(512,2): LDS (69KB) already caps at 2 blocks/CU; the
// 256-VGPR cap avoids spill pressure around the 5-barrier structure.
template<int SLOT>
__global__ __launch_bounds__(512, 2) void expert_kernel(
    const ushortT* __restrict__ xbf, const ushortT* __restrict__ W1bf,
    const ushortT* __restrict__ W2bf, const float* __restrict__ gamma,
    const float* __restrict__ beta, const float* __restrict__ wt,
    const int* __restrict__ cursors, const int* __restrict__ lists,
    float* __restrict__ out)
{
  __shared__ ushortT hX[64 * 512];     // 64 KB shared X-then-h buffer, rows 1024B, slot^(row&7) swizzle
  __shared__ int   toksL[64];
  __shared__ float wrowL[64];
  __shared__ float wsumL[8][64];
  __shared__ float wsqL[8][64];
  __shared__ float muL[64];
  __shared__ float rsL[64];

  int tid = threadIdx.x;
  int w = tid >> 6;
  int l = tid & 63;

  // XCD-chunked bijective swizzle: 2056 = 8*257
  int bid = (int)blockIdx.x;
  bid = (bid & 7) * 257 + (bid >> 3);

  // block -> (expert, tile)
  int e = -1, tile = 0, bacc = 0, cn = 0;
  #pragma unroll
  for (int i = 0; i < 8; i++){
    int c = cursors[SLOT*8 + i];
    int ntl = (c + 63) >> 6;
    if (e < 0 && bid < bacc + ntl){ e = i; tile = bid - bacc; cn = c; }
    bacc += ntl;
  }
  if (e < 0) return;
  int tb = tile * 64;

  if (tid < 64){
    int idx = tb + tid;
    int tok = (idx < cn) ? lists[(size_t)(SLOT*8 + e) * NTOK + idx] : -1;
    toksL[tid] = tok;
    wrowL[tid] = (tok >= 0) ? wt[(size_t)SLOT*NTOK + tok] : 0.f;
  }
  __syncthreads();

  // ---- stage full X tile (64 tok x 512 k) once, swizzled ----
  {
    int r = tid >> 3, cs = tid & 7;
    int tokS = toksL[r]; if (tokS < 0) tokS = toksL[0];
    const int4* xrow = (const int4*)(xbf + (size_t)tokS * 512);
    int4 xv[8];
    #pragma unroll
    for (int i = 0; i < 8; i++) xv[i] = xrow[cs + i*8];
    #pragma unroll
    for (int i = 0; i < 8; i++){
      int slot = cs + i*8;
      int ss = slot ^ (r & 7);
      *(int4*)((char*)hX + r*1024 + ss*16) = xv[i];
    }
  }
  __syncthreads();

  // ---- GEMM1: acc = X @ W1 (wave w owns h-cols w*64..w*64+63), no barriers ----
  const ushortT* w1f = W1bf + ((size_t)(e*32 + w*4))*16*512;
  f32x4 acc[4][4];
  #pragma unroll
  for (int m = 0; m < 4; m++)
    #pragma unroll
    for (int nf = 0; nf < 4; nf++) acc[m][nf] = (f32x4){0.f,0.f,0.f,0.f};

  #pragma unroll 2
  for (int kt = 0; kt < 8; kt++){
    #pragma unroll
    for (int ks = 0; ks < 2; ks++){
      bf16x8 A[4];
      #pragma unroll
      for (int m = 0; m < 4; m++){
        int row = (l & 15) + m*16;
        int slot = kt*8 + ks*4 + (l >> 4);
        A[m] = ldfrag((const char*)hX + row*1024 + (slot ^ (row & 7))*16);
      }
      #pragma unroll
      for (int nf = 0; nf < 4; nf++){
        bf16x8 B = ldfrag(w1f + ((size_t)(nf*16 + kt*2 + ks))*512 + l*8);
        #pragma unroll
        for (int m = 0; m < 4; m++)
          acc[m][nf] = __builtin_amdgcn_mfma_f32_16x16x32_bf16(A[m], B, acc[m][nf], 0, 0, 0);
      }
    }
  }

  // ---- LN partial sums from fp32 acc (regs) ----
  #pragma unroll
  for (int m = 0; m < 4; m++){
    #pragma unroll
    for (int j = 0; j < 4; j++){
      float s = acc[m][0][j] + acc[m][1][j] + acc[m][2][j] + acc[m][3][j];
      float q = acc[m][0][j]*acc[m][0][j] + acc[m][1][j]*acc[m][1][j]
              + acc[m][2][j]*acc[m][2][j] + acc[m][3][j]*acc[m][3][j];
      s += __shfl_xor(s, 1); q += __shfl_xor(q, 1);
      s += __shfl_xor(s, 2); q += __shfl_xor(q, 2);
      s += __shfl_xor(s, 4); q += __shfl_xor(q, 4);
      s += __shfl_xor(s, 8); q += __shfl_xor(q, 8);
      if ((l & 15) == 0){
        int row = m*16 + (l >> 4)*4 + j;
        wsumL[w][row] = s;
        wsqL[w][row]  = q;
      }
    }
  }
  __syncthreads();   // X reads done + partials written

  if (tid < 64){
    float s = 0.f, q = 0.f;
    #pragma unroll
    for (int i = 0; i < 8; i++){ s += wsumL[i][tid]; q += wsqL[i][tid]; }
    float mu = s * (1.f/512.f);
    float var = q * (1.f/512.f) - mu*mu;
    muL[tid] = mu;
    rsL[tid] = rsqrtf(var + 1e-5f);
  }
  __syncthreads();

  // ---- LN + GELU in registers, write h (bf16) into hX (overwrite X) ----
  {
    float g[4], b[4];
    #pragma unroll
    for (int nf = 0; nf < 4; nf++){
      int col = w*64 + nf*16 + (l & 15);
      g[nf] = gamma[e*512 + col];
      b[nf] = beta [e*512 + col];
    }
    #pragma unroll
    for (int m = 0; m < 4; m++){
      #pragma unroll
      for (int j = 0; j < 4; j++){
        int row = m*16 + (l >> 4)*4 + j;
        float mu = muL[row], rs = rsL[row];
        #pragma unroll
        for (int nf = 0; nf < 4; nf++){
          int col = w*64 + nf*16 + (l & 15);
          float v = (acc[m][nf][j] - mu) * rs * g[nf] + b[nf];
          v = gelu_f(v);
          int ss = (col >> 3) ^ (row & 7);
          *(ushortT*)((char*)hX + row*1024 + ss*16 + (col & 7)*2) = f2bfu(v);
        }
      }
    }
  }
  __syncthreads();

  // ---- GEMM2: out-tile = h @ W2, no barriers ----
  const ushortT* w2f = W2bf + ((size_t)(e*32 + w*4))*16*512;
  #pragma unroll
  for (int m = 0; m < 4; m++)
    #pragma unroll
    for (int nf = 0; nf < 4; nf++) acc[m][nf] = (f32x4){0.f,0.f,0.f,0.f};

  #pragma unroll 2
  for (int kt = 0; kt < 8; kt++){
    #pragma unroll
    for (int ks = 0; ks < 2; ks++){
      bf16x8 A[4];
      #pragma unroll
      for (int m = 0; m < 4; m++){
        int row = (l & 15) + m*16;
        int slot = kt*8 + ks*4 + (l >> 4);
        A[m] = ldfrag((const char*)hX + row*1024 + (slot ^ (row & 7))*16);
      }
      #pragma unroll
      for (int nf = 0; nf < 4; nf++){
        bf16x8 B = ldfrag(w2f + ((size_t)(nf*16 + kt*2 + ks))*512 + l*8);
        #pragma unroll
        for (int m = 0; m < 4; m++)
          acc[m][nf] = __builtin_amdgcn_mfma_f32_16x16x32_bf16(A[m], B, acc[m][nf], 0, 0, 0);
      }
    }
  }

  // ---- weighted store ----
  #pragma unroll
  for (int m = 0; m < 4; m++){
    #pragma unroll
    for (int j = 0; j < 4; j++){
      int row = m*16 + (l >> 4)*4 + j;
      int tok = toksL[row];
      if (tok >= 0){
        float wr = wrowL[row];
        #pragma unroll
        for (int nf = 0; nf < 4; nf++){
          int col = w*64 + nf*16 + (l & 15);
          float val = acc[m][nf][j] * wr;
          float* p = out + (size_t)tok*512 + col;
          if (SLOT == 0) *p = val; else *p += val;
        }
      }
    }
  }
}

extern "C" void kernel_launch(void* const* d_in, const int* in_sizes, int n_in,
                              void* d_out, int out_size, void* d_ws, size_t ws_size,
                              hipStream_t stream){
  const float* x     = (const float*)d_in[0];
  const float* Wg    = (const float*)d_in[1];
  const float* W1    = (const float*)d_in[2];
  const float* gamma = (const float*)d_in[3];
  const float* beta  = (const float*)d_in[4];
  const float* W2    = (const float*)d_in[5];
  float* out = (float*)d_out;

  char* ws = (char*)d_ws;
  size_t off = 0;
  ushortT* xbf   = (ushortT*)(ws + off); off += (size_t)NTOK*512*2;      // 128 MB
  ushortT* W1bf  = (ushortT*)(ws + off); off += (size_t)8*512*512*2;     // 4 MB
  ushortT* W2bf  = (ushortT*)(ws + off); off += (size_t)8*512*512*2;     // 4 MB
  int*     lists = (int*)(ws + off);     off += (size_t)16*NTOK*4;       // 8 MB
  float*   wtp   = (float*)(ws + off);   off += (size_t)2*NTOK*4;        // 1 MB
  int*     epair = (int*)(ws + off);     off += (size_t)NTOK*4;          // 0.5 MB
  int*     cursors = (int*)(ws + off);   off += 256;

  zero_cursors_kernel<<<1, 64, 0, stream>>>(cursors);
  prep_w_kernel<<<1024, 256, 0, stream>>>(W1, W2, W1bf, W2bf);
  gating_kernel<<<NTOK/64, 256, 0, stream>>>(x, Wg, xbf, epair, wtp);
  scatter_kernel<<<NTOK/256, 256, 0, stream>>>(epair, cursors, lists);
  expert_kernel<0><<<2056, 512, 0, stream>>>(xbf, W1bf, W2bf, gamma, beta, wtp, cursors, lists, out);
  expert_kernel<1><<<2056, 512, 0, stream>>>(xbf, W1bf, W2bf, gamma, beta, wtp, cursors, lists, out);
}